// Round 6
// baseline (869.292 us; speedup 1.0000x reference)
//
#include <hip/hip_runtime.h>

#define NN 100000
#define NE 1600000

// ---- workspace layout (bytes) ----
// persistent
static constexpr size_t OFF_H0   = 0;                    // [N,64] f32
static constexpr size_t OFF_H1   = 25600000;             // [N,64] f32 (later reused as c2*g2)
static constexpr size_t OFF_H2   = 51200000;             // [N,64] f32
static constexpr size_t OFF_CSR  = 76800000;             // [E] i32
static constexpr size_t OFF_ROW  = 83200000;             // [N+1] i32
static constexpr size_t OFF_NRM  = 83600016;             // [N] f32
static constexpr size_t OFF_INVD = 84000016;             // [N] f32
static constexpr size_t OFF_HH   = 84400016;             // [N] f32 (later g0)
static constexpr size_t OFF_Q0   = 84800016;             // [N] f32 (later g1)
static constexpr size_t OFF_Q1   = 85200016;             // [N] f32
static constexpr size_t OFF_SCR  = 85600016;             // union scratch base
// scratch A (CSR build, dead after merge)
static constexpr size_t OFF_SUBDEG = OFF_SCR;            // [8N] i32
static constexpr size_t OFF_SUBROW = OFF_SCR + 3200000;  // [8N+1] i32
static constexpr size_t OFF_SUBCUR = OFF_SCR + 6400016;  // [8N] i32
static constexpr size_t OFF_SUBCSR = OFF_SCR + 9600016;  // [E] i32
static constexpr size_t OFF_DEG    = OFF_SCR + 16000016; // [N] i32
static constexpr size_t OFF_BSUM   = OFF_SCR + 16400016; // [<=1568] i32
static constexpr size_t OFF_BOFF   = OFF_SCR + 16406288; // [<=1568] i32
// scratch B (layers onward)
static constexpr size_t OFF_C0    = OFF_SCR;             // [N,64] f32
static constexpr size_t OFF_C1    = OFF_SCR + 25600000;  // [N,64] f32
static constexpr size_t OFF_PARTF = OFF_SCR + 51200000;  // [1024,256] f64
static constexpr size_t OFF_MID   = OFF_SCR + 53297152;  // [32,256] f64

// ---- CSR build: XCD-local sub-CSRs ----
__global__ void hist8_kernel(const int* __restrict__ dst, int* __restrict__ subdeg) {
    int e = blockIdx.x * 256 + threadIdx.x;
    int g = blockIdx.x & 7;
    if (e < NE) {
        int d = __builtin_nontemporal_load(&dst[e]);
        atomicAdd(&subdeg[g * NN + d], 1);
    }
}

__global__ void degnorm_kernel(const int* __restrict__ subdeg, int* __restrict__ deg,
                               float* __restrict__ nrm, float* __restrict__ invd) {
    int n = blockIdx.x * 256 + threadIdx.x;
    if (n < NN) {
        int d = 0;
        #pragma unroll
        for (int g = 0; g < 8; ++g) d += subdeg[g * NN + n];
        deg[n] = d;
        float df = (float)max(d, 1);
        nrm[n]  = 1.0f / sqrtf(df);
        invd[n] = 1.0f / df;
    }
}

// ---- generic 3-stage exclusive scan (512-thread blocks) ----
__global__ void scanA_kernel(const int* __restrict__ in, int n, int* __restrict__ outloc,
                             int* __restrict__ bsum) {
    __shared__ int wsum[8], wexcl[8];
    int tid = threadIdx.x, lane = tid & 63, wid = tid >> 6;
    int i = blockIdx.x * 512 + tid;
    int v = (i < n) ? in[i] : 0;
    int x = v;
    #pragma unroll
    for (int off = 1; off < 64; off <<= 1) {
        int y = __shfl_up(x, off);
        if (lane >= off) x += y;
    }
    if (lane == 63) wsum[wid] = x;
    __syncthreads();
    if (tid == 0) {
        int c = 0;
        #pragma unroll
        for (int j = 0; j < 8; ++j) { wexcl[j] = c; c += wsum[j]; }
        bsum[blockIdx.x] = c;
    }
    __syncthreads();
    if (i < n) outloc[i] = (x - v) + wexcl[wid];
}

__global__ void scanB_kernel(const int* __restrict__ bsum, int nb, int* __restrict__ boff,
                             int* __restrict__ total_out) {
    __shared__ int wsum[8], wexcl[8];
    __shared__ int carry;
    int tid = threadIdx.x, lane = tid & 63, wid = tid >> 6;
    if (tid == 0) carry = 0;
    __syncthreads();
    for (int base = 0; base < nb; base += 512) {
        int i = base + tid;
        int v = (i < nb) ? bsum[i] : 0;
        int x = v;
        #pragma unroll
        for (int off = 1; off < 64; off <<= 1) {
            int y = __shfl_up(x, off);
            if (lane >= off) x += y;
        }
        if (lane == 63) wsum[wid] = x;
        __syncthreads();
        if (tid == 0) {
            int c = 0;
            #pragma unroll
            for (int j = 0; j < 8; ++j) { wexcl[j] = c; c += wsum[j]; }
        }
        __syncthreads();
        if (i < nb) boff[i] = carry + wexcl[wid] + (x - v);
        __syncthreads();
        if (tid == 0) carry += wexcl[7] + wsum[7];
        __syncthreads();
    }
    if (tid == 0) *total_out = carry;
}

__global__ void scanC_kernel(int* __restrict__ outloc, const int* __restrict__ boff, int n,
                             int* __restrict__ copy) {
    int i = blockIdx.x * 512 + threadIdx.x;
    if (i < n) {
        int r = outloc[i] + boff[blockIdx.x];
        outloc[i] = r;
        if (copy) copy[i] = r;
    }
}

__global__ void fillB_kernel(const int* __restrict__ src, const int* __restrict__ dst,
                             int* __restrict__ subcur, int* __restrict__ subcsr) {
    int e = blockIdx.x * 256 + threadIdx.x;
    int g = blockIdx.x & 7;
    if (e < NE) {
        int d = __builtin_nontemporal_load(&dst[e]);
        int s = __builtin_nontemporal_load(&src[e]);
        int p = atomicAdd(&subcur[g * NN + d], 1);
        subcsr[p] = s;
    }
}

// concatenate the 8 sub-segments of each node into the global CSR
__global__ void merge_kernel(const int* __restrict__ row_off, const int* __restrict__ subrow,
                             const int* __restrict__ subcur, const int* __restrict__ subcsr,
                             int* __restrict__ csr_src) {
    int n = blockIdx.x * 256 + threadIdx.x;
    if (n >= NN) return;
    int q = row_off[n];
    #pragma unroll
    for (int g = 0; g < 8; ++g) {
        int i = g * NN + n;
        int st = subrow[i], en = subcur[i];
        for (int k = st; k < en; ++k) csr_src[q++] = subcsr[k];
    }
}

// ---- embed: h0 = x @ W_emb.T + b_emb ----
// LDS-tiled register-blocked GEMM: 64-node tile/block, 4x4 per thread.
// All locals are named float4 registers, component access via .x/.y/.z/.w ONLY
// (no address-of on locals -> no scratch; rule #20).
// Macro params must NOT be named x/y/z/w (preprocessor would substitute member tokens).
#define FMA4(a_, s_, v_)                        \
    a_.x = fmaf((s_), (v_).x, a_.x);            \
    a_.y = fmaf((s_), (v_).y, a_.y);            \
    a_.z = fmaf((s_), (v_).z, a_.z);            \
    a_.w = fmaf((s_), (v_).w, a_.w);

__global__ void embed_kernel(const float* __restrict__ x, const float* __restrict__ W,
                             const float* __restrict__ bias, float* __restrict__ h) {
    __shared__ float xs[64 * 68];
    __shared__ float Wt[64 * 68];   // Wt[k][d] = W[d][k]
    const int tid = threadIdx.x;
    for (int i = tid; i < 64 * 64; i += 256) {
        int d = i >> 6, k = i & 63;
        Wt[k * 68 + d] = W[i];
    }
    const int base = blockIdx.x * 64;
    for (int i = tid; i < 64 * 16; i += 256) {
        int r = i >> 4, c4 = i & 15;
        float4 v = make_float4(0.f, 0.f, 0.f, 0.f);
        if (base + r < NN) v = ((const float4*)x)[(size_t)(base + r) * 16 + c4];
        *(float4*)&xs[r * 68 + c4 * 4] = v;
    }
    __syncthreads();
    const int tn = tid >> 4;   // node group 0..15
    const int td = tid & 15;   // dim group 0..15
    const float* xr0 = &xs[(tn * 4 + 0) * 68];
    const float* xr1 = &xs[(tn * 4 + 1) * 68];
    const float* xr2 = &xs[(tn * 4 + 2) * 68];
    const float* xr3 = &xs[(tn * 4 + 3) * 68];
    float4 a0 = make_float4(0.f, 0.f, 0.f, 0.f);
    float4 a1 = a0, a2 = a0, a3 = a0;
    #pragma unroll
    for (int k0 = 0; k0 < 64; k0 += 4) {
        float4 xa0 = *(const float4*)&xr0[k0];
        float4 xa1 = *(const float4*)&xr1[k0];
        float4 xa2 = *(const float4*)&xr2[k0];
        float4 xa3 = *(const float4*)&xr3[k0];
        float4 w0 = *(const float4*)&Wt[(k0 + 0) * 68 + td * 4];
        float4 w1 = *(const float4*)&Wt[(k0 + 1) * 68 + td * 4];
        float4 w2 = *(const float4*)&Wt[(k0 + 2) * 68 + td * 4];
        float4 w3 = *(const float4*)&Wt[(k0 + 3) * 68 + td * 4];
        FMA4(a0, xa0.x, w0); FMA4(a1, xa1.x, w0); FMA4(a2, xa2.x, w0); FMA4(a3, xa3.x, w0);
        FMA4(a0, xa0.y, w1); FMA4(a1, xa1.y, w1); FMA4(a2, xa2.y, w1); FMA4(a3, xa3.y, w1);
        FMA4(a0, xa0.z, w2); FMA4(a1, xa1.z, w2); FMA4(a2, xa2.z, w2); FMA4(a3, xa3.z, w2);
        FMA4(a0, xa0.w, w3); FMA4(a1, xa1.w, w3); FMA4(a2, xa2.w, w3); FMA4(a3, xa3.w, w3);
    }
    float4 bb = ((const float4*)bias)[td];
    a0.x += bb.x; a0.y += bb.y; a0.z += bb.z; a0.w += bb.w;
    a1.x += bb.x; a1.y += bb.y; a1.z += bb.z; a1.w += bb.w;
    a2.x += bb.x; a2.y += bb.y; a2.z += bb.z; a2.w += bb.w;
    a3.x += bb.x; a3.y += bb.y; a3.z += bb.z; a3.w += bb.w;
    int n0 = base + tn * 4;
    if (n0 + 0 < NN) ((float4*)h)[(size_t)(n0 + 0) * 16 + td] = a0;
    if (n0 + 1 < NN) ((float4*)h)[(size_t)(n0 + 1) * 16 + td] = a1;
    if (n0 + 2 < NN) ((float4*)h)[(size_t)(n0 + 2) * 16 + td] = a2;
    if (n0 + 3 < NN) ((float4*)h)[(size_t)(n0 + 3) * 16 + td] = a3;
}

// scalar-broadcast gather: wave-uniform node id -> csr/nrm via SMEM (s_load),
// per-edge work = 1 coalesced 256B vector load + 1 fma
__device__ __forceinline__ float gather_scalar(const float* __restrict__ h,
                                               const int* __restrict__ csr,
                                               const float* __restrict__ nrm,
                                               int start, int end, int lane) {
    float a0 = 0.f, a1 = 0.f, a2 = 0.f, a3 = 0.f;
    int i = start;
    for (; i + 4 <= end; i += 4) {
        int s0 = csr[i], s1 = csr[i + 1], s2 = csr[i + 2], s3 = csr[i + 3];
        float w0 = nrm[s0], w1 = nrm[s1], w2 = nrm[s2], w3 = nrm[s3];
        a0 = fmaf(h[(size_t)s0 * 64 + lane], w0, a0);
        a1 = fmaf(h[(size_t)s1 * 64 + lane], w1, a1);
        a2 = fmaf(h[(size_t)s2 * 64 + lane], w2, a2);
        a3 = fmaf(h[(size_t)s3 * 64 + lane], w3, a3);
    }
    for (; i < end; ++i) {
        int s = csr[i];
        a0 = fmaf(h[(size_t)s * 64 + lane], nrm[s], a0);
    }
    return (a0 + a1) + (a2 + a3);
}

__global__ void layer0_kernel(const float* __restrict__ h0, const int* __restrict__ row_off,
                              const int* __restrict__ csr_src, const float* __restrict__ nrm,
                              const float* __restrict__ invd, float* __restrict__ c0,
                              float* __restrict__ h1, float* __restrict__ hh,
                              float* __restrict__ q0) {
    int wg = __builtin_amdgcn_readfirstlane((blockIdx.x * 256 + threadIdx.x) >> 6);
    int lane = threadIdx.x & 63;
    if (wg >= NN) return;
    float cv = gather_scalar(h0, csr_src, nrm, row_off[wg], row_off[wg + 1], lane) * invd[wg];
    float nm = nrm[wg];
    size_t o = (size_t)wg * 64 + lane;
    float hv = h0[o];
    float hn = hv * nm;
    c0[o] = cv;
    h1[o] = fmaf(cv, nm, hv);
    float sh = hn * hn, sc = cv * cv;
    #pragma unroll
    for (int off = 32; off >= 1; off >>= 1) {
        sh += __shfl_xor(sh, off);
        sc += __shfl_xor(sc, off);
    }
    if (lane == 0) { hh[wg] = sh; q0[wg] = sc; }
}

__global__ void layer1_kernel(const float* __restrict__ h1, const int* __restrict__ row_off,
                              const int* __restrict__ csr_src, const float* __restrict__ nrm,
                              const float* __restrict__ invd, float* __restrict__ c1,
                              float* __restrict__ h2, float* __restrict__ q1) {
    int wg = __builtin_amdgcn_readfirstlane((blockIdx.x * 256 + threadIdx.x) >> 6);
    int lane = threadIdx.x & 63;
    if (wg >= NN) return;
    float cv = gather_scalar(h1, csr_src, nrm, row_off[wg], row_off[wg + 1], lane) * invd[wg];
    float nm = nrm[wg];
    size_t o = (size_t)wg * 64 + lane;
    float hv = h1[o];
    c1[o] = cv;
    h2[o] = fmaf(cv, nm, hv);
    float sc = cv * cv;
    #pragma unroll
    for (int off = 32; off >= 1; off >>= 1) sc += __shfl_xor(sc, off);
    if (lane == 0) q1[wg] = sc;
}

// layer2: gather c2, compute full scalar chain, store c2*g2 (into dead h1 buffer),
// overwrite hh<-g0, q0<-g1
__global__ void layer2_kernel(const float* __restrict__ h2, const int* __restrict__ row_off,
                              const int* __restrict__ csr_src, const float* __restrict__ nrm,
                              const float* __restrict__ invd, float* __restrict__ hh,
                              float* __restrict__ q0, const float* __restrict__ q1,
                              float* __restrict__ c2g) {
    int wg = __builtin_amdgcn_readfirstlane((blockIdx.x * 256 + threadIdx.x) >> 6);
    int lane = threadIdx.x & 63;
    if (wg >= NN) return;
    float cv = gather_scalar(h2, csr_src, nrm, row_off[wg], row_off[wg + 1], lane) * invd[wg];
    float q2 = cv * cv;
    #pragma unroll
    for (int off = 32; off >= 1; off >>= 1) q2 += __shfl_xor(q2, off);
    float hh0 = hh[wg], q0v = q0[wg], q1v = q1[wg];
    const float EPS = 1e-12f;
    float n0s = hh0 + q0v;
    float s0 = fmaxf(sqrtf(n0s), EPS);
    float r1s = n0s / (s0 * s0) + q1v;
    float s1 = fmaxf(sqrtf(r1s), EPS);
    float r2s = r1s / (s1 * s1) + q2;
    float s2 = fmaxf(sqrtf(r2s), EPS);
    float g2 = 1.0f / s2;
    float g1 = 1.0f / (s1 * s2);
    float g0 = g1 / s0;
    c2g[(size_t)wg * 64 + lane] = cv * g2;
    if (lane == 0) { hh[wg] = g0; q0[wg] = g1; }
}

// weighted column sums of the final bundle, fixed-order f64 partials
__global__ void colsum_final(const float* __restrict__ h0, const float* __restrict__ c0,
                             const float* __restrict__ c1, const float* __restrict__ c2g,
                             const float* __restrict__ nrm, const float* __restrict__ g0a,
                             const float* __restrict__ g1a, double* __restrict__ partialF) {
    __shared__ double lds[256];
    int tid = threadIdx.x, lane = tid & 63, wid = tid >> 6;
    double a0 = 0.0, a1 = 0.0, a2 = 0.0, a3 = 0.0;
    for (int n = blockIdx.x * 4 + wid; n < NN; n += gridDim.x * 4) {
        float nm = nrm[n], g0 = g0a[n], g1 = g1a[n];
        size_t o = (size_t)n * 64 + lane;
        float hn = h0[o] * nm;
        a0 += (double)(hn * g0);
        a1 += (double)(c0[o] * g0);
        a2 += (double)(c1[o] * g1);
        a3 += (double)c2g[o];
    }
    #pragma unroll
    for (int seg = 0; seg < 4; ++seg) {
        double v = (seg == 0) ? a0 : (seg == 1) ? a1 : (seg == 2) ? a2 : a3;
        lds[tid] = v;
        __syncthreads();
        if (wid == 0)
            partialF[(size_t)blockIdx.x * 256 + seg * 64 + lane] =
                lds[lane] + lds[64 + lane] + lds[128 + lane] + lds[192 + lane];
        __syncthreads();
    }
}

__global__ void reduceP_kernel(const double* __restrict__ partialF, double* __restrict__ mid) {
    int t = threadIdx.x;
    double acc = 0.0;
    for (int j = 0; j < 32; ++j)
        acc += partialF[((size_t)blockIdx.x * 32 + j) * 256 + t];
    mid[(size_t)blockIdx.x * 256 + t] = acc;
}

__global__ void final_kernel(const double* __restrict__ mid, const float* __restrict__ W_lin,
                             const float* __restrict__ b_lin, const float* __restrict__ W_out,
                             const float* __restrict__ b_out, float* __restrict__ out) {
    __shared__ double cs[256];
    __shared__ double hg[64];
    int t = threadIdx.x;  // 256
    double acc = 0.0;
    for (int b = 0; b < 32; ++b) acc += mid[b * 256 + t];
    cs[t] = acc;
    __syncthreads();
    if (t < 64) {
        const double invN = 1.0 / (double)NN;
        double a = (double)b_lin[t];
        for (int k = 0; k < 256; ++k) a += cs[k] * invN * (double)W_lin[t * 256 + k];
        hg[t] = a;
    }
    __syncthreads();
    if (t < 10) {
        double o = (double)b_out[t];
        for (int k = 0; k < 64; ++k) o += hg[k] * (double)W_out[t * 64 + k];
        out[t] = (float)o;
    }
}

extern "C" void kernel_launch(void* const* d_in, const int* in_sizes, int n_in,
                              void* d_out, int out_size, void* d_ws, size_t ws_size,
                              hipStream_t stream) {
    const float* x     = (const float*)d_in[0];
    const int*   src   = (const int*)d_in[1];
    const int*   dst   = (const int*)d_in[2];
    const float* W_emb = (const float*)d_in[3];
    const float* b_emb = (const float*)d_in[4];
    const float* W_lin = (const float*)d_in[5];
    const float* b_lin = (const float*)d_in[6];
    const float* W_out = (const float*)d_in[7];
    const float* b_out = (const float*)d_in[8];
    float* out = (float*)d_out;

    char* ws = (char*)d_ws;
    float*  h0      = (float*)(ws + OFF_H0);
    float*  h1      = (float*)(ws + OFF_H1);
    float*  h2      = (float*)(ws + OFF_H2);
    int*    csr_src = (int*)(ws + OFF_CSR);
    int*    row_off = (int*)(ws + OFF_ROW);
    float*  nrm     = (float*)(ws + OFF_NRM);
    float*  invd    = (float*)(ws + OFF_INVD);
    float*  hh      = (float*)(ws + OFF_HH);
    float*  q0      = (float*)(ws + OFF_Q0);
    float*  q1      = (float*)(ws + OFF_Q1);
    int*    subdeg  = (int*)(ws + OFF_SUBDEG);
    int*    subrow  = (int*)(ws + OFF_SUBROW);
    int*    subcur  = (int*)(ws + OFF_SUBCUR);
    int*    subcsr  = (int*)(ws + OFF_SUBCSR);
    int*    deg     = (int*)(ws + OFF_DEG);
    int*    bsum    = (int*)(ws + OFF_BSUM);
    int*    boff    = (int*)(ws + OFF_BOFF);
    float*  c0      = (float*)(ws + OFF_C0);
    float*  c1      = (float*)(ws + OFF_C1);
    double* partialF= (double*)(ws + OFF_PARTF);
    double* mid     = (double*)(ws + OFF_MID);

    hipMemsetAsync(subdeg, 0, (size_t)8 * NN * 4, stream);

    const int edgeBlocks = (NE + 255) / 256;            // 6250
    hist8_kernel<<<edgeBlocks, 256, 0, stream>>>(dst, subdeg);
    degnorm_kernel<<<(NN + 255) / 256, 256, 0, stream>>>(subdeg, deg, nrm, invd);

    // scan subdeg[8N] -> subrow (+ copy to subcur)
    const int sb8 = (8 * NN + 511) / 512;               // 1563
    scanA_kernel<<<sb8, 512, 0, stream>>>(subdeg, 8 * NN, subrow, bsum);
    scanB_kernel<<<1, 512, 0, stream>>>(bsum, sb8, boff, subrow + 8 * NN);
    scanC_kernel<<<sb8, 512, 0, stream>>>(subrow, boff, 8 * NN, subcur);
    // scan deg[N] -> row_off
    const int sbN = (NN + 511) / 512;                   // 196
    scanA_kernel<<<sbN, 512, 0, stream>>>(deg, NN, row_off, bsum);
    scanB_kernel<<<1, 512, 0, stream>>>(bsum, sbN, boff, row_off + NN);
    scanC_kernel<<<sbN, 512, 0, stream>>>(row_off, boff, NN, (int*)nullptr);

    fillB_kernel<<<edgeBlocks, 256, 0, stream>>>(src, dst, subcur, subcsr);
    merge_kernel<<<(NN + 255) / 256, 256, 0, stream>>>(row_off, subrow, subcur, subcsr, csr_src);

    embed_kernel<<<(NN + 63) / 64, 256, 0, stream>>>(x, W_emb, b_emb, h0);

    const int nodeBlocks = (NN * 64 + 255) / 256;       // wave per node
    layer0_kernel<<<nodeBlocks, 256, 0, stream>>>(h0, row_off, csr_src, nrm, invd, c0, h1, hh, q0);
    layer1_kernel<<<nodeBlocks, 256, 0, stream>>>(h1, row_off, csr_src, nrm, invd, c1, h2, q1);
    layer2_kernel<<<nodeBlocks, 256, 0, stream>>>(h2, row_off, csr_src, nrm, invd, hh, q0, q1, h1);

    colsum_final<<<1024, 256, 0, stream>>>(h0, c0, c1, h1, nrm, hh, q0, partialF);
    reduceP_kernel<<<32, 256, 0, stream>>>(partialF, mid);
    final_kernel<<<1, 256, 0, stream>>>(mid, W_lin, b_lin, W_out, b_out, out);
}

// Round 7
// 429.920 us; speedup vs baseline: 2.0220x; 2.0220x over previous
//
#include <hip/hip_runtime.h>

#define NN 100000
#define NE 1600000

// ---- workspace layout (bytes) ----
// persistent
static constexpr size_t OFF_H0   = 0;                    // [N,64] f32
static constexpr size_t OFF_H1   = 25600000;             // [N,64] f32 (later reused as c2*g2)
static constexpr size_t OFF_H2   = 51200000;             // [N,64] f32
static constexpr size_t OFF_CSR  = 76800000;             // [E] i32
static constexpr size_t OFF_ROW  = 83200000;             // [N+1] i32
static constexpr size_t OFF_NRM  = 83600016;             // [N] f32
static constexpr size_t OFF_INVD = 84000016;             // [N] f32
static constexpr size_t OFF_HH   = 84400016;             // [N] f32 (later g0)
static constexpr size_t OFF_Q0   = 84800016;             // [N] f32 (later g1)
static constexpr size_t OFF_Q1   = 85200016;             // [N] f32
static constexpr size_t OFF_SCR  = 85600016;             // union scratch base
// scratch A (CSR build, dead after merge)
static constexpr size_t OFF_SUBDEG = OFF_SCR;            // [8N] i32
static constexpr size_t OFF_SUBROW = OFF_SCR + 3200000;  // [8N+1] i32
static constexpr size_t OFF_SUBCUR = OFF_SCR + 6400016;  // [8N] i32
static constexpr size_t OFF_SUBCSR = OFF_SCR + 9600016;  // [E] i32
static constexpr size_t OFF_DEG    = OFF_SCR + 16000016; // [N] i32
static constexpr size_t OFF_BSUM   = OFF_SCR + 16400016; // [<=1568] i32
static constexpr size_t OFF_BOFF   = OFF_SCR + 16406288; // [<=1568] i32
// scratch B (layers onward)
static constexpr size_t OFF_C0    = OFF_SCR;             // [N,64] f32
static constexpr size_t OFF_C1    = OFF_SCR + 25600000;  // [N,64] f32
static constexpr size_t OFF_PARTF = OFF_SCR + 51200000;  // [1024,256] f64
static constexpr size_t OFF_MID   = OFF_SCR + 53297152;  // [32,256] f64

// ---- CSR build: XCD-local sub-CSRs ----
__global__ void hist8_kernel(const int* __restrict__ dst, int* __restrict__ subdeg) {
    int e = blockIdx.x * 256 + threadIdx.x;
    int g = blockIdx.x & 7;
    if (e < NE) {
        int d = __builtin_nontemporal_load(&dst[e]);
        atomicAdd(&subdeg[g * NN + d], 1);
    }
}

__global__ void degnorm_kernel(const int* __restrict__ subdeg, int* __restrict__ deg,
                               float* __restrict__ nrm, float* __restrict__ invd) {
    int n = blockIdx.x * 256 + threadIdx.x;
    if (n < NN) {
        int d = 0;
        #pragma unroll
        for (int g = 0; g < 8; ++g) d += subdeg[g * NN + n];
        deg[n] = d;
        float df = (float)max(d, 1);
        nrm[n]  = 1.0f / sqrtf(df);
        invd[n] = 1.0f / df;
    }
}

// ---- generic 3-stage exclusive scan (512-thread blocks) ----
__global__ void scanA_kernel(const int* __restrict__ in, int n, int* __restrict__ outloc,
                             int* __restrict__ bsum) {
    __shared__ int wsum[8], wexcl[8];
    int tid = threadIdx.x, lane = tid & 63, wid = tid >> 6;
    int i = blockIdx.x * 512 + tid;
    int v = (i < n) ? in[i] : 0;
    int x = v;
    #pragma unroll
    for (int off = 1; off < 64; off <<= 1) {
        int y = __shfl_up(x, off);
        if (lane >= off) x += y;
    }
    if (lane == 63) wsum[wid] = x;
    __syncthreads();
    if (tid == 0) {
        int c = 0;
        #pragma unroll
        for (int j = 0; j < 8; ++j) { wexcl[j] = c; c += wsum[j]; }
        bsum[blockIdx.x] = c;
    }
    __syncthreads();
    if (i < n) outloc[i] = (x - v) + wexcl[wid];
}

__global__ void scanB_kernel(const int* __restrict__ bsum, int nb, int* __restrict__ boff,
                             int* __restrict__ total_out) {
    __shared__ int wsum[8], wexcl[8];
    __shared__ int carry;
    int tid = threadIdx.x, lane = tid & 63, wid = tid >> 6;
    if (tid == 0) carry = 0;
    __syncthreads();
    for (int base = 0; base < nb; base += 512) {
        int i = base + tid;
        int v = (i < nb) ? bsum[i] : 0;
        int x = v;
        #pragma unroll
        for (int off = 1; off < 64; off <<= 1) {
            int y = __shfl_up(x, off);
            if (lane >= off) x += y;
        }
        if (lane == 63) wsum[wid] = x;
        __syncthreads();
        if (tid == 0) {
            int c = 0;
            #pragma unroll
            for (int j = 0; j < 8; ++j) { wexcl[j] = c; c += wsum[j]; }
        }
        __syncthreads();
        if (i < nb) boff[i] = carry + wexcl[wid] + (x - v);
        __syncthreads();
        if (tid == 0) carry += wexcl[7] + wsum[7];
        __syncthreads();
    }
    if (tid == 0) *total_out = carry;
}

__global__ void scanC_kernel(int* __restrict__ outloc, const int* __restrict__ boff, int n,
                             int* __restrict__ copy) {
    int i = blockIdx.x * 512 + threadIdx.x;
    if (i < n) {
        int r = outloc[i] + boff[blockIdx.x];
        outloc[i] = r;
        if (copy) copy[i] = r;
    }
}

__global__ void fillB_kernel(const int* __restrict__ src, const int* __restrict__ dst,
                             int* __restrict__ subcur, int* __restrict__ subcsr) {
    int e = blockIdx.x * 256 + threadIdx.x;
    int g = blockIdx.x & 7;
    if (e < NE) {
        int d = __builtin_nontemporal_load(&dst[e]);
        int s = __builtin_nontemporal_load(&src[e]);
        int p = atomicAdd(&subcur[g * NN + d], 1);
        subcsr[p] = s;
    }
}

// concatenate the 8 sub-segments of each node into the global CSR
__global__ void merge_kernel(const int* __restrict__ row_off, const int* __restrict__ subrow,
                             const int* __restrict__ subcur, const int* __restrict__ subcsr,
                             int* __restrict__ csr_src) {
    int n = blockIdx.x * 256 + threadIdx.x;
    if (n >= NN) return;
    int q = row_off[n];
    #pragma unroll
    for (int g = 0; g < 8; ++g) {
        int i = g * NN + n;
        int st = subrow[i], en = subcur[i];
        for (int k = st; k < en; ++k) csr_src[q++] = subcsr[k];
    }
}

// ---- embed: h0 = x @ W_emb.T + b_emb ----
// LDS-tiled register-blocked GEMM: 64-node tile/block, 4x4 per thread.
// k0 loop kept ROLLED (#pragma unroll 1): full unroll hoisted 128 float4 LDS
// loads -> live-range explosion past the 64-VGPR occupancy cap -> 1.4GB of
// scratch spill traffic (round 4/6 counters). Rolled body = 8 ds_read_b128 +
// 64 fma, ~50 VGPR live, no spill.
#define FMA4(a_, s_, v_)                        \
    a_.x = fmaf((s_), (v_).x, a_.x);            \
    a_.y = fmaf((s_), (v_).y, a_.y);            \
    a_.z = fmaf((s_), (v_).z, a_.z);            \
    a_.w = fmaf((s_), (v_).w, a_.w);

__global__ void embed_kernel(const float* __restrict__ x, const float* __restrict__ W,
                             const float* __restrict__ bias, float* __restrict__ h) {
    __shared__ __align__(16) float xs[64 * 68];
    __shared__ __align__(16) float Wt[64 * 68];   // Wt[k][d] = W[d][k]
    const int tid = threadIdx.x;
    for (int i = tid; i < 64 * 64; i += 256) {
        int d = i >> 6, k = i & 63;
        Wt[k * 68 + d] = W[i];
    }
    const int base = blockIdx.x * 64;
    for (int i = tid; i < 64 * 16; i += 256) {
        int r = i >> 4, c4 = i & 15;
        float4 v = make_float4(0.f, 0.f, 0.f, 0.f);
        if (base + r < NN) v = ((const float4*)x)[(size_t)(base + r) * 16 + c4];
        *(float4*)&xs[r * 68 + c4 * 4] = v;
    }
    __syncthreads();
    const int tn = tid >> 4;   // node group 0..15
    const int td = tid & 15;   // dim group 0..15
    const float* xr0 = &xs[(tn * 4 + 0) * 68];
    const float* xr1 = &xs[(tn * 4 + 1) * 68];
    const float* xr2 = &xs[(tn * 4 + 2) * 68];
    const float* xr3 = &xs[(tn * 4 + 3) * 68];
    float4 a0 = make_float4(0.f, 0.f, 0.f, 0.f);
    float4 a1 = a0, a2 = a0, a3 = a0;
    #pragma unroll 1
    for (int k0 = 0; k0 < 64; k0 += 4) {
        float4 xa0 = *(const float4*)&xr0[k0];
        float4 xa1 = *(const float4*)&xr1[k0];
        float4 xa2 = *(const float4*)&xr2[k0];
        float4 xa3 = *(const float4*)&xr3[k0];
        float4 w0 = *(const float4*)&Wt[(k0 + 0) * 68 + td * 4];
        float4 w1 = *(const float4*)&Wt[(k0 + 1) * 68 + td * 4];
        float4 w2 = *(const float4*)&Wt[(k0 + 2) * 68 + td * 4];
        float4 w3 = *(const float4*)&Wt[(k0 + 3) * 68 + td * 4];
        FMA4(a0, xa0.x, w0); FMA4(a1, xa1.x, w0); FMA4(a2, xa2.x, w0); FMA4(a3, xa3.x, w0);
        FMA4(a0, xa0.y, w1); FMA4(a1, xa1.y, w1); FMA4(a2, xa2.y, w1); FMA4(a3, xa3.y, w1);
        FMA4(a0, xa0.z, w2); FMA4(a1, xa1.z, w2); FMA4(a2, xa2.z, w2); FMA4(a3, xa3.z, w2);
        FMA4(a0, xa0.w, w3); FMA4(a1, xa1.w, w3); FMA4(a2, xa2.w, w3); FMA4(a3, xa3.w, w3);
    }
    float4 bb = ((const float4*)bias)[td];
    a0.x += bb.x; a0.y += bb.y; a0.z += bb.z; a0.w += bb.w;
    a1.x += bb.x; a1.y += bb.y; a1.z += bb.z; a1.w += bb.w;
    a2.x += bb.x; a2.y += bb.y; a2.z += bb.z; a2.w += bb.w;
    a3.x += bb.x; a3.y += bb.y; a3.z += bb.z; a3.w += bb.w;
    int n0 = base + tn * 4;
    if (n0 + 0 < NN) ((float4*)h)[(size_t)(n0 + 0) * 16 + td] = a0;
    if (n0 + 1 < NN) ((float4*)h)[(size_t)(n0 + 1) * 16 + td] = a1;
    if (n0 + 2 < NN) ((float4*)h)[(size_t)(n0 + 2) * 16 + td] = a2;
    if (n0 + 3 < NN) ((float4*)h)[(size_t)(n0 + 3) * 16 + td] = a3;
}

// scalar-broadcast gather: wave-uniform node id -> csr/nrm via SMEM (s_load),
// per-edge work = 1 coalesced 256B vector load + 1 fma
__device__ __forceinline__ float gather_scalar(const float* __restrict__ h,
                                               const int* __restrict__ csr,
                                               const float* __restrict__ nrm,
                                               int start, int end, int lane) {
    float a0 = 0.f, a1 = 0.f, a2 = 0.f, a3 = 0.f;
    int i = start;
    for (; i + 4 <= end; i += 4) {
        int s0 = csr[i], s1 = csr[i + 1], s2 = csr[i + 2], s3 = csr[i + 3];
        float w0 = nrm[s0], w1 = nrm[s1], w2 = nrm[s2], w3 = nrm[s3];
        a0 = fmaf(h[(size_t)s0 * 64 + lane], w0, a0);
        a1 = fmaf(h[(size_t)s1 * 64 + lane], w1, a1);
        a2 = fmaf(h[(size_t)s2 * 64 + lane], w2, a2);
        a3 = fmaf(h[(size_t)s3 * 64 + lane], w3, a3);
    }
    for (; i < end; ++i) {
        int s = csr[i];
        a0 = fmaf(h[(size_t)s * 64 + lane], nrm[s], a0);
    }
    return (a0 + a1) + (a2 + a3);
}

__global__ void layer0_kernel(const float* __restrict__ h0, const int* __restrict__ row_off,
                              const int* __restrict__ csr_src, const float* __restrict__ nrm,
                              const float* __restrict__ invd, float* __restrict__ c0,
                              float* __restrict__ h1, float* __restrict__ hh,
                              float* __restrict__ q0) {
    int wg = __builtin_amdgcn_readfirstlane((blockIdx.x * 256 + threadIdx.x) >> 6);
    int lane = threadIdx.x & 63;
    if (wg >= NN) return;
    float cv = gather_scalar(h0, csr_src, nrm, row_off[wg], row_off[wg + 1], lane) * invd[wg];
    float nm = nrm[wg];
    size_t o = (size_t)wg * 64 + lane;
    float hv = h0[o];
    float hn = hv * nm;
    c0[o] = cv;
    h1[o] = fmaf(cv, nm, hv);
    float sh = hn * hn, sc = cv * cv;
    #pragma unroll
    for (int off = 32; off >= 1; off >>= 1) {
        sh += __shfl_xor(sh, off);
        sc += __shfl_xor(sc, off);
    }
    if (lane == 0) { hh[wg] = sh; q0[wg] = sc; }
}

__global__ void layer1_kernel(const float* __restrict__ h1, const int* __restrict__ row_off,
                              const int* __restrict__ csr_src, const float* __restrict__ nrm,
                              const float* __restrict__ invd, float* __restrict__ c1,
                              float* __restrict__ h2, float* __restrict__ q1) {
    int wg = __builtin_amdgcn_readfirstlane((blockIdx.x * 256 + threadIdx.x) >> 6);
    int lane = threadIdx.x & 63;
    if (wg >= NN) return;
    float cv = gather_scalar(h1, csr_src, nrm, row_off[wg], row_off[wg + 1], lane) * invd[wg];
    float nm = nrm[wg];
    size_t o = (size_t)wg * 64 + lane;
    float hv = h1[o];
    c1[o] = cv;
    h2[o] = fmaf(cv, nm, hv);
    float sc = cv * cv;
    #pragma unroll
    for (int off = 32; off >= 1; off >>= 1) sc += __shfl_xor(sc, off);
    if (lane == 0) q1[wg] = sc;
}

// layer2: gather c2, compute full scalar chain, store c2*g2 (into dead h1 buffer),
// overwrite hh<-g0, q0<-g1
__global__ void layer2_kernel(const float* __restrict__ h2, const int* __restrict__ row_off,
                              const int* __restrict__ csr_src, const float* __restrict__ nrm,
                              const float* __restrict__ invd, float* __restrict__ hh,
                              float* __restrict__ q0, const float* __restrict__ q1,
                              float* __restrict__ c2g) {
    int wg = __builtin_amdgcn_readfirstlane((blockIdx.x * 256 + threadIdx.x) >> 6);
    int lane = threadIdx.x & 63;
    if (wg >= NN) return;
    float cv = gather_scalar(h2, csr_src, nrm, row_off[wg], row_off[wg + 1], lane) * invd[wg];
    float q2 = cv * cv;
    #pragma unroll
    for (int off = 32; off >= 1; off >>= 1) q2 += __shfl_xor(q2, off);
    float hh0 = hh[wg], q0v = q0[wg], q1v = q1[wg];
    const float EPS = 1e-12f;
    float n0s = hh0 + q0v;
    float s0 = fmaxf(sqrtf(n0s), EPS);
    float r1s = n0s / (s0 * s0) + q1v;
    float s1 = fmaxf(sqrtf(r1s), EPS);
    float r2s = r1s / (s1 * s1) + q2;
    float s2 = fmaxf(sqrtf(r2s), EPS);
    float g2 = 1.0f / s2;
    float g1 = 1.0f / (s1 * s2);
    float g0 = g1 / s0;
    c2g[(size_t)wg * 64 + lane] = cv * g2;
    if (lane == 0) { hh[wg] = g0; q0[wg] = g1; }
}

// weighted column sums of the final bundle, fixed-order f64 partials
__global__ void colsum_final(const float* __restrict__ h0, const float* __restrict__ c0,
                             const float* __restrict__ c1, const float* __restrict__ c2g,
                             const float* __restrict__ nrm, const float* __restrict__ g0a,
                             const float* __restrict__ g1a, double* __restrict__ partialF) {
    __shared__ double lds[256];
    int tid = threadIdx.x, lane = tid & 63, wid = tid >> 6;
    double a0 = 0.0, a1 = 0.0, a2 = 0.0, a3 = 0.0;
    for (int n = blockIdx.x * 4 + wid; n < NN; n += gridDim.x * 4) {
        float nm = nrm[n], g0 = g0a[n], g1 = g1a[n];
        size_t o = (size_t)n * 64 + lane;
        float hn = h0[o] * nm;
        a0 += (double)(hn * g0);
        a1 += (double)(c0[o] * g0);
        a2 += (double)(c1[o] * g1);
        a3 += (double)c2g[o];
    }
    #pragma unroll
    for (int seg = 0; seg < 4; ++seg) {
        double v = (seg == 0) ? a0 : (seg == 1) ? a1 : (seg == 2) ? a2 : a3;
        lds[tid] = v;
        __syncthreads();
        if (wid == 0)
            partialF[(size_t)blockIdx.x * 256 + seg * 64 + lane] =
                lds[lane] + lds[64 + lane] + lds[128 + lane] + lds[192 + lane];
        __syncthreads();
    }
}

__global__ void reduceP_kernel(const double* __restrict__ partialF, double* __restrict__ mid) {
    int t = threadIdx.x;
    double acc = 0.0;
    for (int j = 0; j < 32; ++j)
        acc += partialF[((size_t)blockIdx.x * 32 + j) * 256 + t];
    mid[(size_t)blockIdx.x * 256 + t] = acc;
}

__global__ void final_kernel(const double* __restrict__ mid, const float* __restrict__ W_lin,
                             const float* __restrict__ b_lin, const float* __restrict__ W_out,
                             const float* __restrict__ b_out, float* __restrict__ out) {
    __shared__ double cs[256];
    __shared__ double hg[64];
    int t = threadIdx.x;  // 256
    double acc = 0.0;
    for (int b = 0; b < 32; ++b) acc += mid[b * 256 + t];
    cs[t] = acc;
    __syncthreads();
    if (t < 64) {
        const double invN = 1.0 / (double)NN;
        double a = (double)b_lin[t];
        for (int k = 0; k < 256; ++k) a += cs[k] * invN * (double)W_lin[t * 256 + k];
        hg[t] = a;
    }
    __syncthreads();
    if (t < 10) {
        double o = (double)b_out[t];
        for (int k = 0; k < 64; ++k) o += hg[k] * (double)W_out[t * 64 + k];
        out[t] = (float)o;
    }
}

extern "C" void kernel_launch(void* const* d_in, const int* in_sizes, int n_in,
                              void* d_out, int out_size, void* d_ws, size_t ws_size,
                              hipStream_t stream) {
    const float* x     = (const float*)d_in[0];
    const int*   src   = (const int*)d_in[1];
    const int*   dst   = (const int*)d_in[2];
    const float* W_emb = (const float*)d_in[3];
    const float* b_emb = (const float*)d_in[4];
    const float* W_lin = (const float*)d_in[5];
    const float* b_lin = (const float*)d_in[6];
    const float* W_out = (const float*)d_in[7];
    const float* b_out = (const float*)d_in[8];
    float* out = (float*)d_out;

    char* ws = (char*)d_ws;
    float*  h0      = (float*)(ws + OFF_H0);
    float*  h1      = (float*)(ws + OFF_H1);
    float*  h2      = (float*)(ws + OFF_H2);
    int*    csr_src = (int*)(ws + OFF_CSR);
    int*    row_off = (int*)(ws + OFF_ROW);
    float*  nrm     = (float*)(ws + OFF_NRM);
    float*  invd    = (float*)(ws + OFF_INVD);
    float*  hh      = (float*)(ws + OFF_HH);
    float*  q0      = (float*)(ws + OFF_Q0);
    float*  q1      = (float*)(ws + OFF_Q1);
    int*    subdeg  = (int*)(ws + OFF_SUBDEG);
    int*    subrow  = (int*)(ws + OFF_SUBROW);
    int*    subcur  = (int*)(ws + OFF_SUBCUR);
    int*    subcsr  = (int*)(ws + OFF_SUBCSR);
    int*    deg     = (int*)(ws + OFF_DEG);
    int*    bsum    = (int*)(ws + OFF_BSUM);
    int*    boff    = (int*)(ws + OFF_BOFF);
    float*  c0      = (float*)(ws + OFF_C0);
    float*  c1      = (float*)(ws + OFF_C1);
    double* partialF= (double*)(ws + OFF_PARTF);
    double* mid     = (double*)(ws + OFF_MID);

    hipMemsetAsync(subdeg, 0, (size_t)8 * NN * 4, stream);

    const int edgeBlocks = (NE + 255) / 256;            // 6250
    hist8_kernel<<<edgeBlocks, 256, 0, stream>>>(dst, subdeg);
    degnorm_kernel<<<(NN + 255) / 256, 256, 0, stream>>>(subdeg, deg, nrm, invd);

    // scan subdeg[8N] -> subrow (+ copy to subcur)
    const int sb8 = (8 * NN + 511) / 512;               // 1563
    scanA_kernel<<<sb8, 512, 0, stream>>>(subdeg, 8 * NN, subrow, bsum);
    scanB_kernel<<<1, 512, 0, stream>>>(bsum, sb8, boff, subrow + 8 * NN);
    scanC_kernel<<<sb8, 512, 0, stream>>>(subrow, boff, 8 * NN, subcur);
    // scan deg[N] -> row_off
    const int sbN = (NN + 511) / 512;                   // 196
    scanA_kernel<<<sbN, 512, 0, stream>>>(deg, NN, row_off, bsum);
    scanB_kernel<<<1, 512, 0, stream>>>(bsum, sbN, boff, row_off + NN);
    scanC_kernel<<<sbN, 512, 0, stream>>>(row_off, boff, NN, (int*)nullptr);

    fillB_kernel<<<edgeBlocks, 256, 0, stream>>>(src, dst, subcur, subcsr);
    merge_kernel<<<(NN + 255) / 256, 256, 0, stream>>>(row_off, subrow, subcur, subcsr, csr_src);

    embed_kernel<<<(NN + 63) / 64, 256, 0, stream>>>(x, W_emb, b_emb, h0);

    const int nodeBlocks = (NN * 64 + 255) / 256;       // wave per node
    layer0_kernel<<<nodeBlocks, 256, 0, stream>>>(h0, row_off, csr_src, nrm, invd, c0, h1, hh, q0);
    layer1_kernel<<<nodeBlocks, 256, 0, stream>>>(h1, row_off, csr_src, nrm, invd, c1, h2, q1);
    layer2_kernel<<<nodeBlocks, 256, 0, stream>>>(h2, row_off, csr_src, nrm, invd, hh, q0, q1, h1);

    colsum_final<<<1024, 256, 0, stream>>>(h0, c0, c1, h1, nrm, hh, q0, partialF);
    reduceP_kernel<<<32, 256, 0, stream>>>(partialF, mid);
    final_kernel<<<1, 256, 0, stream>>>(mid, W_lin, b_lin, W_out, b_out, out);
}

// Round 8
// 417.371 us; speedup vs baseline: 2.0828x; 1.0301x over previous
//
#include <hip/hip_runtime.h>

#define NN 100000
#define NE 1600000

// ---- workspace layout (bytes) ----
// persistent
static constexpr size_t OFF_H0   = 0;                     // [N,64] f32
static constexpr size_t OFF_H1   = 25600000;              // [N,64] f32
static constexpr size_t OFF_H2   = 51200000;              // [N,64] f32
static constexpr size_t OFF_CSRP = 76800000;              // [E] (int src, f32 w) pairs = 12.8MB
static constexpr size_t OFF_ROW  = 89600000;              // [N+1] i32
static constexpr size_t OFF_NRM  = 90000064;              // [N] f32
static constexpr size_t OFF_INVD = 90400064;              // [N] f32
static constexpr size_t OFF_HH   = 90800064;              // [N] f32
static constexpr size_t OFF_Q0   = 91200064;              // [N] f32
static constexpr size_t OFF_Q1   = 91600064;              // [N] f32
static constexpr size_t OFF_SCR  = 92000064;              // union scratch base
// scratch A (CSR build, dead after merge)
static constexpr size_t OFF_SUBDEG = OFF_SCR;             // [8N] i32
static constexpr size_t OFF_SUBROW = OFF_SCR + 3200000;   // [8N+1] i32
static constexpr size_t OFF_SUBCUR = OFF_SCR + 6400080;   // [8N] i32
static constexpr size_t OFF_SUBCSR = OFF_SCR + 9600080;   // [E] i32
static constexpr size_t OFF_DEG    = OFF_SCR + 16000080;  // [N] i32
static constexpr size_t OFF_BSUM   = OFF_SCR + 16400080;  // [<=2048] i32
static constexpr size_t OFF_BOFF   = OFF_SCR + 16408272;  // [<=2048] i32
// scratch B (layers onward)
static constexpr size_t OFF_PARTF = OFF_SCR;              // [2048,256] f64 = 4MB
static constexpr size_t OFF_MID   = OFF_SCR + 4194304;    // [32,256] f64

// ---- CSR build: XCD-local sub-CSRs ----
__global__ void hist8_kernel(const int* __restrict__ dst, int* __restrict__ subdeg) {
    int e = blockIdx.x * 256 + threadIdx.x;
    int g = blockIdx.x & 7;
    if (e < NE) {
        int d = __builtin_nontemporal_load(&dst[e]);
        atomicAdd(&subdeg[g * NN + d], 1);
    }
}

__global__ void degnorm_kernel(const int* __restrict__ subdeg, int* __restrict__ deg,
                               float* __restrict__ nrm, float* __restrict__ invd) {
    int n = blockIdx.x * 256 + threadIdx.x;
    if (n < NN) {
        int d = 0;
        #pragma unroll
        for (int g = 0; g < 8; ++g) d += subdeg[g * NN + n];
        deg[n] = d;
        float df = (float)max(d, 1);
        nrm[n]  = 1.0f / sqrtf(df);
        invd[n] = 1.0f / df;
    }
}

// ---- generic 3-stage exclusive scan (512-thread blocks) ----
__global__ void scanA_kernel(const int* __restrict__ in, int n, int* __restrict__ outloc,
                             int* __restrict__ bsum) {
    __shared__ int wsum[8], wexcl[8];
    int tid = threadIdx.x, lane = tid & 63, wid = tid >> 6;
    int i = blockIdx.x * 512 + tid;
    int v = (i < n) ? in[i] : 0;
    int x = v;
    #pragma unroll
    for (int off = 1; off < 64; off <<= 1) {
        int y = __shfl_up(x, off);
        if (lane >= off) x += y;
    }
    if (lane == 63) wsum[wid] = x;
    __syncthreads();
    if (tid == 0) {
        int c = 0;
        #pragma unroll
        for (int j = 0; j < 8; ++j) { wexcl[j] = c; c += wsum[j]; }
        bsum[blockIdx.x] = c;
    }
    __syncthreads();
    if (i < n) outloc[i] = (x - v) + wexcl[wid];
}

__global__ void scanB_kernel(const int* __restrict__ bsum, int nb, int* __restrict__ boff,
                             int* __restrict__ total_out) {
    __shared__ int wsum[8], wexcl[8];
    __shared__ int carry;
    int tid = threadIdx.x, lane = tid & 63, wid = tid >> 6;
    if (tid == 0) carry = 0;
    __syncthreads();
    for (int base = 0; base < nb; base += 512) {
        int i = base + tid;
        int v = (i < nb) ? bsum[i] : 0;
        int x = v;
        #pragma unroll
        for (int off = 1; off < 64; off <<= 1) {
            int y = __shfl_up(x, off);
            if (lane >= off) x += y;
        }
        if (lane == 63) wsum[wid] = x;
        __syncthreads();
        if (tid == 0) {
            int c = 0;
            #pragma unroll
            for (int j = 0; j < 8; ++j) { wexcl[j] = c; c += wsum[j]; }
        }
        __syncthreads();
        if (i < nb) boff[i] = carry + wexcl[wid] + (x - v);
        __syncthreads();
        if (tid == 0) carry += wexcl[7] + wsum[7];
        __syncthreads();
    }
    if (tid == 0) *total_out = carry;
}

__global__ void scanC_kernel(int* __restrict__ outloc, const int* __restrict__ boff, int n,
                             int* __restrict__ copy) {
    int i = blockIdx.x * 512 + threadIdx.x;
    if (i < n) {
        int r = outloc[i] + boff[blockIdx.x];
        outloc[i] = r;
        if (copy) copy[i] = r;
    }
}

__global__ void fillB_kernel(const int* __restrict__ src, const int* __restrict__ dst,
                             int* __restrict__ subcur, int* __restrict__ subcsr) {
    int e = blockIdx.x * 256 + threadIdx.x;
    int g = blockIdx.x & 7;
    if (e < NE) {
        int d = __builtin_nontemporal_load(&dst[e]);
        int s = __builtin_nontemporal_load(&src[e]);
        int p = atomicAdd(&subcur[g * NN + d], 1);
        subcsr[p] = s;
    }
}

// output-centric merge: thread per CSR slot p, binary search node, writes (src, w) pair
__global__ void merge_bs_kernel(const int* __restrict__ row_off, const int* __restrict__ subrow,
                                const int* __restrict__ subcur, const int* __restrict__ subcsr,
                                const float* __restrict__ nrm, int* __restrict__ csrp) {
    int p = blockIdx.x * 256 + threadIdx.x;
    if (p >= NE) return;
    int lo = 0, hi = NN;   // row_off[NN] = NE
    while (lo + 1 < hi) {
        int mid = (lo + hi) >> 1;
        if (row_off[mid] <= p) lo = mid; else hi = mid;
    }
    int n = lo;
    int local = p - row_off[n];
    int s = 0;
    #pragma unroll
    for (int g = 0; g < 8; ++g) {
        int base = g * NN + n;
        int st = subrow[base];
        int len = subcur[base] - st;
        if (local < len) { s = subcsr[st + local]; break; }
        local -= len;
    }
    csrp[2 * p]     = s;
    csrp[2 * p + 1] = __float_as_int(nrm[s]);
}

// ---- embed: h0 = x @ W_emb.T + b_emb (rolled k-loop, no spill) ----
#define FMA4(a_, s_, v_)                        \
    a_.x = fmaf((s_), (v_).x, a_.x);            \
    a_.y = fmaf((s_), (v_).y, a_.y);            \
    a_.z = fmaf((s_), (v_).z, a_.z);            \
    a_.w = fmaf((s_), (v_).w, a_.w);

__global__ void embed_kernel(const float* __restrict__ x, const float* __restrict__ W,
                             const float* __restrict__ bias, float* __restrict__ h) {
    __shared__ __align__(16) float xs[64 * 68];
    __shared__ __align__(16) float Wt[64 * 68];   // Wt[k][d] = W[d][k]
    const int tid = threadIdx.x;
    for (int i = tid; i < 64 * 64; i += 256) {
        int d = i >> 6, k = i & 63;
        Wt[k * 68 + d] = W[i];
    }
    const int base = blockIdx.x * 64;
    for (int i = tid; i < 64 * 16; i += 256) {
        int r = i >> 4, c4 = i & 15;
        float4 v = make_float4(0.f, 0.f, 0.f, 0.f);
        if (base + r < NN) v = ((const float4*)x)[(size_t)(base + r) * 16 + c4];
        *(float4*)&xs[r * 68 + c4 * 4] = v;
    }
    __syncthreads();
    const int tn = tid >> 4;
    const int td = tid & 15;
    const float* xr0 = &xs[(tn * 4 + 0) * 68];
    const float* xr1 = &xs[(tn * 4 + 1) * 68];
    const float* xr2 = &xs[(tn * 4 + 2) * 68];
    const float* xr3 = &xs[(tn * 4 + 3) * 68];
    float4 a0 = make_float4(0.f, 0.f, 0.f, 0.f);
    float4 a1 = a0, a2 = a0, a3 = a0;
    #pragma unroll 1
    for (int k0 = 0; k0 < 64; k0 += 4) {
        float4 xa0 = *(const float4*)&xr0[k0];
        float4 xa1 = *(const float4*)&xr1[k0];
        float4 xa2 = *(const float4*)&xr2[k0];
        float4 xa3 = *(const float4*)&xr3[k0];
        float4 w0 = *(const float4*)&Wt[(k0 + 0) * 68 + td * 4];
        float4 w1 = *(const float4*)&Wt[(k0 + 1) * 68 + td * 4];
        float4 w2 = *(const float4*)&Wt[(k0 + 2) * 68 + td * 4];
        float4 w3 = *(const float4*)&Wt[(k0 + 3) * 68 + td * 4];
        FMA4(a0, xa0.x, w0); FMA4(a1, xa1.x, w0); FMA4(a2, xa2.x, w0); FMA4(a3, xa3.x, w0);
        FMA4(a0, xa0.y, w1); FMA4(a1, xa1.y, w1); FMA4(a2, xa2.y, w1); FMA4(a3, xa3.y, w1);
        FMA4(a0, xa0.z, w2); FMA4(a1, xa1.z, w2); FMA4(a2, xa2.z, w2); FMA4(a3, xa3.z, w2);
        FMA4(a0, xa0.w, w3); FMA4(a1, xa1.w, w3); FMA4(a2, xa2.w, w3); FMA4(a3, xa3.w, w3);
    }
    float4 bb = ((const float4*)bias)[td];
    a0.x += bb.x; a0.y += bb.y; a0.z += bb.z; a0.w += bb.w;
    a1.x += bb.x; a1.y += bb.y; a1.z += bb.z; a1.w += bb.w;
    a2.x += bb.x; a2.y += bb.y; a2.z += bb.z; a2.w += bb.w;
    a3.x += bb.x; a3.y += bb.y; a3.z += bb.z; a3.w += bb.w;
    int n0 = base + tn * 4;
    if (n0 + 0 < NN) ((float4*)h)[(size_t)(n0 + 0) * 16 + td] = a0;
    if (n0 + 1 < NN) ((float4*)h)[(size_t)(n0 + 1) * 16 + td] = a1;
    if (n0 + 2 < NN) ((float4*)h)[(size_t)(n0 + 2) * 16 + td] = a2;
    if (n0 + 3 < NN) ((float4*)h)[(size_t)(n0 + 3) * 16 + td] = a3;
}

// gather with packed (src,w) pairs: all index/weight loads wave-uniform contiguous s_loads
__device__ __forceinline__ float gather_pair(const float* __restrict__ h,
                                             const int* __restrict__ csrp,
                                             int start, int end, int lane) {
    float a0 = 0.f, a1 = 0.f, a2 = 0.f, a3 = 0.f;
    int i = start;
    for (; i + 8 <= end; i += 8) {
        int s0 = csrp[2*i+0];  float w0 = __int_as_float(csrp[2*i+1]);
        int s1 = csrp[2*i+2];  float w1 = __int_as_float(csrp[2*i+3]);
        int s2 = csrp[2*i+4];  float w2 = __int_as_float(csrp[2*i+5]);
        int s3 = csrp[2*i+6];  float w3 = __int_as_float(csrp[2*i+7]);
        int s4 = csrp[2*i+8];  float w4 = __int_as_float(csrp[2*i+9]);
        int s5 = csrp[2*i+10]; float w5 = __int_as_float(csrp[2*i+11]);
        int s6 = csrp[2*i+12]; float w6 = __int_as_float(csrp[2*i+13]);
        int s7 = csrp[2*i+14]; float w7 = __int_as_float(csrp[2*i+15]);
        a0 = fmaf(h[(size_t)s0 * 64 + lane], w0, a0);
        a1 = fmaf(h[(size_t)s1 * 64 + lane], w1, a1);
        a2 = fmaf(h[(size_t)s2 * 64 + lane], w2, a2);
        a3 = fmaf(h[(size_t)s3 * 64 + lane], w3, a3);
        a0 = fmaf(h[(size_t)s4 * 64 + lane], w4, a0);
        a1 = fmaf(h[(size_t)s5 * 64 + lane], w5, a1);
        a2 = fmaf(h[(size_t)s6 * 64 + lane], w6, a2);
        a3 = fmaf(h[(size_t)s7 * 64 + lane], w7, a3);
    }
    for (; i + 2 <= end; i += 2) {
        int s0 = csrp[2*i+0]; float w0 = __int_as_float(csrp[2*i+1]);
        int s1 = csrp[2*i+2]; float w1 = __int_as_float(csrp[2*i+3]);
        a0 = fmaf(h[(size_t)s0 * 64 + lane], w0, a0);
        a1 = fmaf(h[(size_t)s1 * 64 + lane], w1, a1);
    }
    if (i < end) {
        int s0 = csrp[2*i+0]; float w0 = __int_as_float(csrp[2*i+1]);
        a0 = fmaf(h[(size_t)s0 * 64 + lane], w0, a0);
    }
    return (a0 + a1) + (a2 + a3);
}

// layer0: gather c0 (not stored); h1 = h0 + c0*nm; hh=||h0*nm||^2, q0=||c0||^2
__global__ void layer0_kernel(const float* __restrict__ h0, const int* __restrict__ row_off,
                              const int* __restrict__ csrp, const float* __restrict__ nrm,
                              const float* __restrict__ invd, float* __restrict__ h1,
                              float* __restrict__ hh, float* __restrict__ q0) {
    int wg = __builtin_amdgcn_readfirstlane((blockIdx.x * 256 + threadIdx.x) >> 6);
    int lane = threadIdx.x & 63;
    if (wg >= NN) return;
    float cv = gather_pair(h0, csrp, row_off[wg], row_off[wg + 1], lane) * invd[wg];
    float nm = nrm[wg];
    size_t o = (size_t)wg * 64 + lane;
    float hv = h0[o];
    float hn = hv * nm;
    h1[o] = fmaf(cv, nm, hv);
    float sh = hn * hn, sc = cv * cv;
    #pragma unroll
    for (int off = 32; off >= 1; off >>= 1) {
        sh += __shfl_xor(sh, off);
        sc += __shfl_xor(sc, off);
    }
    if (lane == 0) { hh[wg] = sh; q0[wg] = sc; }
}

// layer1: gather c1 (not stored); h2 = h1 + c1*nm; q1=||c1||^2
__global__ void layer1_kernel(const float* __restrict__ h1, const int* __restrict__ row_off,
                              const int* __restrict__ csrp, const float* __restrict__ nrm,
                              const float* __restrict__ invd, float* __restrict__ h2,
                              float* __restrict__ q1) {
    int wg = __builtin_amdgcn_readfirstlane((blockIdx.x * 256 + threadIdx.x) >> 6);
    int lane = threadIdx.x & 63;
    if (wg >= NN) return;
    float cv = gather_pair(h1, csrp, row_off[wg], row_off[wg + 1], lane) * invd[wg];
    float nm = nrm[wg];
    size_t o = (size_t)wg * 64 + lane;
    float hv = h1[o];
    h2[o] = fmaf(cv, nm, hv);
    float sc = cv * cv;
    #pragma unroll
    for (int off = 32; off >= 1; off >>= 1) sc += __shfl_xor(sc, off);
    if (lane == 0) q1[wg] = sc;
}

// layer2 fused with weighted colsum: gather c2; q2 reduce; g-chain; recover
// c0=(h1-h0)/nm, c1=(h2-h1)/nm; accumulate f64 colsum partials per block.
__global__ void layer2_fused(const float* __restrict__ h0, const float* __restrict__ h1,
                             const float* __restrict__ h2, const int* __restrict__ row_off,
                             const int* __restrict__ csrp, const float* __restrict__ nrm,
                             const float* __restrict__ invd, const float* __restrict__ hh,
                             const float* __restrict__ q0, const float* __restrict__ q1,
                             double* __restrict__ partialF) {
    __shared__ double lds[256];
    int tid = threadIdx.x, lane = tid & 63, wid = tid >> 6;
    double A0 = 0.0, A1 = 0.0, A2 = 0.0, A3 = 0.0;
    const float EPS = 1e-12f;
    for (int nb = blockIdx.x * 4 + wid; nb < NN; nb += gridDim.x * 4) {
        int wg = __builtin_amdgcn_readfirstlane(nb);
        float cv = gather_pair(h2, csrp, row_off[wg], row_off[wg + 1], lane) * invd[wg];
        float sc = cv * cv;
        #pragma unroll
        for (int off = 32; off >= 1; off >>= 1) sc += __shfl_xor(sc, off);
        float n0s = hh[wg] + q0[wg];
        float s0 = fmaxf(sqrtf(n0s), EPS);
        float r1s = n0s / (s0 * s0) + q1[wg];
        float s1 = fmaxf(sqrtf(r1s), EPS);
        float r2s = r1s / (s1 * s1) + sc;
        float s2 = fmaxf(sqrtf(r2s), EPS);
        float g2 = 1.0f / s2;
        float g1 = 1.0f / (s1 * s2);
        float g0 = g1 / s0;
        float nm = nrm[wg];
        float isq = 1.0f / nm;
        size_t o = (size_t)wg * 64 + lane;
        float h0v = h0[o], h1v = h1[o], h2v = h2[o];
        float hn = h0v * nm;
        float c0r = (h1v - h0v) * isq;
        float c1r = (h2v - h1v) * isq;
        A0 += (double)(hn * g0);
        A1 += (double)(c0r * g0);
        A2 += (double)(c1r * g1);
        A3 += (double)(cv * g2);
    }
    #pragma unroll
    for (int seg = 0; seg < 4; ++seg) {
        double v = (seg == 0) ? A0 : (seg == 1) ? A1 : (seg == 2) ? A2 : A3;
        lds[tid] = v;
        __syncthreads();
        if (wid == 0)
            partialF[(size_t)blockIdx.x * 256 + seg * 64 + lane] =
                lds[lane] + lds[64 + lane] + lds[128 + lane] + lds[192 + lane];
        __syncthreads();
    }
}

__global__ void reduceP_kernel(const double* __restrict__ partialF, double* __restrict__ mid) {
    int t = threadIdx.x;
    double acc = 0.0;
    for (int j = 0; j < 64; ++j)
        acc += partialF[((size_t)blockIdx.x * 64 + j) * 256 + t];
    mid[(size_t)blockIdx.x * 256 + t] = acc;
}

__global__ void final_kernel(const double* __restrict__ mid, const float* __restrict__ W_lin,
                             const float* __restrict__ b_lin, const float* __restrict__ W_out,
                             const float* __restrict__ b_out, float* __restrict__ out) {
    __shared__ double cs[256];
    __shared__ double hg[64];
    int t = threadIdx.x;  // 256
    double acc = 0.0;
    for (int b = 0; b < 32; ++b) acc += mid[b * 256 + t];
    cs[t] = acc;
    __syncthreads();
    if (t < 64) {
        const double invN = 1.0 / (double)NN;
        double a = (double)b_lin[t];
        for (int k = 0; k < 256; ++k) a += cs[k] * invN * (double)W_lin[t * 256 + k];
        hg[t] = a;
    }
    __syncthreads();
    if (t < 10) {
        double o = (double)b_out[t];
        for (int k = 0; k < 64; ++k) o += hg[k] * (double)W_out[t * 64 + k];
        out[t] = (float)o;
    }
}

extern "C" void kernel_launch(void* const* d_in, const int* in_sizes, int n_in,
                              void* d_out, int out_size, void* d_ws, size_t ws_size,
                              hipStream_t stream) {
    const float* x     = (const float*)d_in[0];
    const int*   src   = (const int*)d_in[1];
    const int*   dst   = (const int*)d_in[2];
    const float* W_emb = (const float*)d_in[3];
    const float* b_emb = (const float*)d_in[4];
    const float* W_lin = (const float*)d_in[5];
    const float* b_lin = (const float*)d_in[6];
    const float* W_out = (const float*)d_in[7];
    const float* b_out = (const float*)d_in[8];
    float* out = (float*)d_out;

    char* ws = (char*)d_ws;
    float*  h0      = (float*)(ws + OFF_H0);
    float*  h1      = (float*)(ws + OFF_H1);
    float*  h2      = (float*)(ws + OFF_H2);
    int*    csrp    = (int*)(ws + OFF_CSRP);
    int*    row_off = (int*)(ws + OFF_ROW);
    float*  nrm     = (float*)(ws + OFF_NRM);
    float*  invd    = (float*)(ws + OFF_INVD);
    float*  hh      = (float*)(ws + OFF_HH);
    float*  q0      = (float*)(ws + OFF_Q0);
    float*  q1      = (float*)(ws + OFF_Q1);
    int*    subdeg  = (int*)(ws + OFF_SUBDEG);
    int*    subrow  = (int*)(ws + OFF_SUBROW);
    int*    subcur  = (int*)(ws + OFF_SUBCUR);
    int*    subcsr  = (int*)(ws + OFF_SUBCSR);
    int*    deg     = (int*)(ws + OFF_DEG);
    int*    bsum    = (int*)(ws + OFF_BSUM);
    int*    boff    = (int*)(ws + OFF_BOFF);
    double* partialF= (double*)(ws + OFF_PARTF);
    double* mid     = (double*)(ws + OFF_MID);

    hipMemsetAsync(subdeg, 0, (size_t)8 * NN * 4, stream);

    const int edgeBlocks = (NE + 255) / 256;            // 6250
    hist8_kernel<<<edgeBlocks, 256, 0, stream>>>(dst, subdeg);
    degnorm_kernel<<<(NN + 255) / 256, 256, 0, stream>>>(subdeg, deg, nrm, invd);

    // scan subdeg[8N] -> subrow (+ copy to subcur)
    const int sb8 = (8 * NN + 511) / 512;               // 1563
    scanA_kernel<<<sb8, 512, 0, stream>>>(subdeg, 8 * NN, subrow, bsum);
    scanB_kernel<<<1, 512, 0, stream>>>(bsum, sb8, boff, subrow + 8 * NN);
    scanC_kernel<<<sb8, 512, 0, stream>>>(subrow, boff, 8 * NN, subcur);
    // scan deg[N] -> row_off
    const int sbN = (NN + 511) / 512;                   // 196
    scanA_kernel<<<sbN, 512, 0, stream>>>(deg, NN, row_off, bsum);
    scanB_kernel<<<1, 512, 0, stream>>>(bsum, sbN, boff, row_off + NN);
    scanC_kernel<<<sbN, 512, 0, stream>>>(row_off, boff, NN, (int*)nullptr);

    fillB_kernel<<<edgeBlocks, 256, 0, stream>>>(src, dst, subcur, subcsr);
    merge_bs_kernel<<<edgeBlocks, 256, 0, stream>>>(row_off, subrow, subcur, subcsr, nrm, csrp);

    embed_kernel<<<(NN + 63) / 64, 256, 0, stream>>>(x, W_emb, b_emb, h0);

    const int nodeBlocks = (NN * 64 + 255) / 256;       // wave per node
    layer0_kernel<<<nodeBlocks, 256, 0, stream>>>(h0, row_off, csrp, nrm, invd, h1, hh, q0);
    layer1_kernel<<<nodeBlocks, 256, 0, stream>>>(h1, row_off, csrp, nrm, invd, h2, q1);
    layer2_fused<<<2048, 256, 0, stream>>>(h0, h1, h2, row_off, csrp, nrm, invd, hh, q0, q1,
                                           partialF);

    reduceP_kernel<<<32, 256, 0, stream>>>(partialF, mid);
    final_kernel<<<1, 256, 0, stream>>>(mid, W_lin, b_lin, W_out, b_out, out);
}